// Round 1
// baseline (106.135 us; speedup 1.0000x reference)
//
#include <hip/hip_runtime.h>

// RGCN HighMem: out[dst[e]] += feat[src[e]] @ W[etypes[e]]
// E=200000, N=50000, R=64, D=32.
//
// Baseline structure: one 32-lane group per edge; lane o owns output col o.
// feat row broadcast via __shfl(width=32); W rows read coalesced (lane o ->
// W[r][i][o], consecutive across lanes). Scatter via global atomicAdd
// (device-scope by default on CDNA4 -> correct across XCDs).

#define D 32

__global__ __launch_bounds__(256) void rgcn_edge_kernel(
    const float* __restrict__ feat,
    const float* __restrict__ weight,
    const int*   __restrict__ src,
    const int*   __restrict__ dst,
    const int*   __restrict__ etypes,
    float*       __restrict__ out,
    int n_edges)
{
    int gid = blockIdx.x * blockDim.x + threadIdx.x;
    int e = gid >> 5;          // edge index (32 lanes per edge)
    int o = gid & 31;          // output column
    if (e >= n_edges) return;

    int s = src[e];
    int d = dst[e];
    int r = etypes[e];

    const float* W = weight + (size_t)r * (D * D);

    // Each lane holds one element of the source feature row; broadcast via
    // half-wave shuffle so we issue 1 global load instead of 32 per lane.
    float fv = feat[(size_t)s * D + o];

    float acc = 0.f;
    #pragma unroll
    for (int i = 0; i < D; ++i) {
        float fi = __shfl(fv, i, 32);          // broadcast feat[s][i]
        acc = fmaf(fi, W[i * D + o], acc);     // coalesced W row read
    }

    atomicAdd(&out[(size_t)d * D + o], acc);
}

extern "C" void kernel_launch(void* const* d_in, const int* in_sizes, int n_in,
                              void* d_out, int out_size, void* d_ws, size_t ws_size,
                              hipStream_t stream) {
    const float* feat   = (const float*)d_in[0];
    const float* weight = (const float*)d_in[1];
    const int*   src    = (const int*)d_in[2];
    const int*   dst    = (const int*)d_in[3];
    const int*   etypes = (const int*)d_in[4];
    float*       out    = (float*)d_out;

    int n_edges = in_sizes[2];

    // d_out is poisoned with 0xAA before every timed launch -> zero it.
    hipMemsetAsync(d_out, 0, (size_t)out_size * sizeof(float), stream);

    long long total_threads = (long long)n_edges * 32;
    int block = 256;
    int grid = (int)((total_threads + block - 1) / block);
    rgcn_edge_kernel<<<grid, block, 0, stream>>>(feat, weight, src, dst, etypes,
                                                 out, n_edges);
}